// Round 1
// baseline (488.314 us; speedup 1.0000x reference)
//
#include <hip/hip_runtime.h>

typedef unsigned short ushort_t;
typedef short short8 __attribute__((ext_vector_type(8)));
typedef unsigned short ushort8 __attribute__((ext_vector_type(8)));
typedef float floatx4 __attribute__((ext_vector_type(4)));

#define N_W 589824   // 256*256*3*3

static __device__ __forceinline__ unsigned short f2bf(float f) {
    unsigned int u = __float_as_uint(f);
    u = (u + 0x7FFFu + ((u >> 16) & 1u)) >> 16;   // round-to-nearest-even
    return (unsigned short)u;
}

// ---------------- kernel 1: sum(|w|) -> double in ws[0] ----------------
__global__ void absmean_kernel(const float* __restrict__ w, double* __restrict__ dsum) {
    int tid = blockIdx.x * blockDim.x + threadIdx.x;
    int stride = gridDim.x * blockDim.x;
    float local = 0.f;
    for (int i = tid; i < N_W; i += stride) local += fabsf(w[i]);
    for (int off = 32; off > 0; off >>= 1)
        local += __shfl_down(local, off, 64);
    __shared__ float part[4];
    int lane = threadIdx.x & 63, wv = threadIdx.x >> 6;
    if (lane == 0) part[wv] = local;
    __syncthreads();
    if (threadIdx.x == 0) {
        float s = part[0] + part[1] + part[2] + part[3];
        atomicAdd(dsum, (double)s);  // double: delta must be bit-stable vs np ref
    }
}

// ------------- kernel 2: ternarize + transpose to [r][co][cin] bf16 -------------
__global__ void ternarize_kernel(const float* __restrict__ w, const double* __restrict__ dsum,
                                 ushort_t* __restrict__ wt) {
    int o = blockIdx.x * 256 + threadIdx.x;          // o = (r*256+co)*256+cin
    float delta = 0.7f * (float)(*dsum / (double)N_W);
    int cin = o & 255;
    int co  = (o >> 8) & 255;
    int r   = o >> 16;                               // 0..8
    float v = w[(co * 256 + cin) * 9 + r];
    float t = (v > delta) ? 1.f : ((v < -delta) ? -1.f : 0.f);
    wt[o] = f2bf(t);
}

// ------------- kernel 3: shift-conv as 9 GEMMs, bf16 MFMA -------------
// grid: x = 28 (7 h-tiles x 4 w-tiles), y = 32 (batch), z = 2 (co block of 128)
// block: 256 threads = 4 waves; wave tile = 64 co x 64 px
__global__ __launch_bounds__(256, 2)
void conv_mfma_kernel(const float* __restrict__ x, const ushort_t* __restrict__ wt,
                      const float* __restrict__ alpha, const float* __restrict__ bias,
                      float* __restrict__ out) {
    // x halo tile: 10 rows x 18 cols x 32 cin (padded to 40 -> b128 reads are 2-way/free)
    __shared__ __align__(16) ushort_t lds_x[10 * 18 * 40];
    __shared__ __align__(16) ushort_t lds_a[128 * 40];

    const int tid  = threadIdx.x;
    const int b    = blockIdx.y;
    const int th   = blockIdx.x >> 2;       // 0..6
    const int tw   = blockIdx.x & 3;        // 0..3 (tile 3 ragged: cols 48..63)
    const int h0   = th * 8;
    const int w0   = tw * 16;
    const int co0  = blockIdx.z * 128;

    const int lane = tid & 63;
    const int wave = tid >> 6;
    const int l15  = lane & 15;
    const int quad = lane >> 4;
    const int wco  = (wave & 1) * 64;       // wave co offset within block tile
    const int wrow = (wave >> 1) * 4;       // wave row offset (rows 0-3 or 4-7)

    floatx4 acc[4][4];
#pragma unroll
    for (int i = 0; i < 4; ++i)
#pragma unroll
        for (int j = 0; j < 4; ++j)
            acc[i][j] = (floatx4){0.f, 0.f, 0.f, 0.f};

    const int co_l = tid >> 1;              // 0..127, A-staging row
    const int half = tid & 1;               // which 16-cin half

    for (int cin0 = 0; cin0 < 256; cin0 += 32) {
        // ---- stage x halo (fp32 -> bf16), 10*18*32 = 5760 elements ----
        for (int e = tid; e < 5760; e += 256) {
            int hc = e % 18;
            int t2 = e / 18;
            int hr = t2 % 10;
            int ci = t2 / 10;
            int hh = h0 - 1 + hr;
            int ww = w0 - 1 + hc;
            float v = 0.f;
            if (hh >= 0 && hh < 56 && ww >= 0 && ww < 56)
                v = x[((b * 256 + cin0 + ci) * 3136) + hh * 56 + ww];
            lds_x[(hr * 18 + hc) * 40 + ci] = f2bf(v);
        }
        for (int r9 = 0; r9 < 9; ++r9) {
            // ---- stage A tile: 128 co x 32 cin of ternary bf16 ----
            {
                const ushort8* src = (const ushort8*)(wt + (((r9 * 256) + co0 + co_l) * 256 + cin0 + half * 16));
                ushort8 v0 = src[0];
                ushort8 v1 = src[1];
                *(ushort8*)&lds_a[co_l * 40 + half * 16]     = v0;
                *(ushort8*)&lds_a[co_l * 40 + half * 16 + 8] = v1;
            }
            __syncthreads();   // covers x-stage (r9==0) and A-stage
            const int kh = r9 / 3;
            const int kw = r9 % 3;
            short8 af[4], bf[4];
#pragma unroll
            for (int j = 0; j < 4; ++j) {
                int hr = wrow + j + kh;          // shifted halo row
                int hc = l15 + kw;               // shifted halo col
                bf[j] = *(const short8*)&lds_x[(hr * 18 + hc) * 40 + quad * 8];
            }
#pragma unroll
            for (int i = 0; i < 4; ++i) {
                int co = wco + i * 16 + l15;
                af[i] = *(const short8*)&lds_a[co * 40 + quad * 8];
            }
#pragma unroll
            for (int i = 0; i < 4; ++i)
#pragma unroll
                for (int j = 0; j < 4; ++j)
                    acc[i][j] = __builtin_amdgcn_mfma_f32_16x16x32_bf16(af[i], bf[j], acc[i][j], 0, 0, 0);
            __syncthreads();   // protect lds_a (and lds_x on last r9) before restage
        }
    }

    // ---- epilogue: D row = quad*4+reg (co), col = l15 (w) ----
    const float a0 = alpha[0];
#pragma unroll
    for (int i = 0; i < 4; ++i) {
        int cob = co0 + wco + i * 16 + quad * 4;
#pragma unroll
        for (int j = 0; j < 4; ++j) {
            int hh = h0 + wrow + j;
            int ww = w0 + l15;
            if (ww < 56) {
#pragma unroll
                for (int r = 0; r < 4; ++r) {
                    int cog = cob + r;
                    out[((b * 256 + cog) * 56 + hh) * 56 + ww] = acc[i][j][r] * a0 + bias[cog];
                }
            }
        }
    }
}

extern "C" void kernel_launch(void* const* d_in, const int* in_sizes, int n_in,
                              void* d_out, int out_size, void* d_ws, size_t ws_size,
                              hipStream_t stream) {
    const float* x      = (const float*)d_in[0];
    const float* weight = (const float*)d_in[1];
    const float* alpha  = (const float*)d_in[2];
    const float* bias   = (const float*)d_in[3];
    float* out = (float*)d_out;

    double*   dsum = (double*)d_ws;
    ushort_t* wt   = (ushort_t*)((char*)d_ws + 16);   // 9*256*256 bf16 = 1.18 MB

    hipMemsetAsync(d_ws, 0, 16, stream);
    absmean_kernel<<<256, 256, 0, stream>>>(weight, dsum);
    ternarize_kernel<<<N_W / 256, 256, 0, stream>>>(weight, dsum, wt);

    dim3 grid(28, 32, 2);
    conv_mfma_kernel<<<grid, 256, 0, stream>>>(x, wt, alpha, bias, out);
}

// Round 2
// 481.963 us; speedup vs baseline: 1.0132x; 1.0132x over previous
//
#include <hip/hip_runtime.h>

typedef unsigned short ushort_t;
typedef short short8 __attribute__((ext_vector_type(8)));
typedef float floatx4 __attribute__((ext_vector_type(4)));

#define N_W 589824   // 256*256*3*3

static __device__ __forceinline__ unsigned short f2bf(float f) {
    unsigned int u = __float_as_uint(f);
    u = (u + 0x7FFFu + ((u >> 16) & 1u)) >> 16;   // round-to-nearest-even
    return (unsigned short)u;
}

// async 16B global -> LDS DMA (global_load_lds_dwordx4). LDS dst must be
// wave-uniform base; data lands at base + lane*16.
static __device__ __forceinline__ void g2l16(const void* g, void* lds_base_uniform) {
    __builtin_amdgcn_global_load_lds(
        (__attribute__((address_space(1))) void*)g,
        (__attribute__((address_space(3))) void*)lds_base_uniform,
        16, 0, 0);
}

// ---------------- kernel 1: sum(|w|) -> double in ws[0] ----------------
__global__ void absmean_kernel(const float* __restrict__ w, double* __restrict__ dsum) {
    int tid = blockIdx.x * blockDim.x + threadIdx.x;
    int stride = gridDim.x * blockDim.x;
    float local = 0.f;
    for (int i = tid; i < N_W; i += stride) local += fabsf(w[i]);
    for (int off = 32; off > 0; off >>= 1)
        local += __shfl_down(local, off, 64);
    __shared__ float part[4];
    int lane = threadIdx.x & 63, wv = threadIdx.x >> 6;
    if (lane == 0) part[wv] = local;
    __syncthreads();
    if (threadIdx.x == 0) {
        float s = part[0] + part[1] + part[2] + part[3];
        atomicAdd(dsum, (double)s);  // double: delta must be bit-stable vs np ref
    }
}

// ------------- kernel 2: ternarize + transpose to [r][co][cin] bf16 -------------
__global__ void ternarize_kernel(const float* __restrict__ w, const double* __restrict__ dsum,
                                 ushort_t* __restrict__ wt) {
    int o = blockIdx.x * 256 + threadIdx.x;          // o = (r*256+co)*256+cin
    float delta = 0.7f * (float)(*dsum / (double)N_W);
    int cin = o & 255;
    int co  = (o >> 8) & 255;
    int r   = o >> 16;                               // 0..8
    float v = w[(co * 256 + cin) * 9 + r];
    float t = (v > delta) ? 1.f : ((v < -delta) ? -1.f : 0.f);
    wt[o] = f2bf(t);
}

// ------- kernel 3a: zero the 1px border of padded NHWC bf16 x -------
__global__ void border_zero_kernel(ushort_t* __restrict__ xp) {
    int e = blockIdx.x * 256 + threadIdx.x;          // 32*228*256 = 1867776
    int ci   = e & 255;
    int rest = e >> 8;                               // 0..7295 = 32*228
    int pid  = rest % 228;
    int b    = rest / 228;
    int hh, ww;
    if (pid < 58)       { hh = 0;  ww = pid; }
    else if (pid < 116) { hh = 57; ww = pid - 58; }
    else {
        int p = pid - 116;                           // 0..111
        hh = 1 + (p >> 1);
        ww = (p & 1) ? 57 : 0;
    }
    xp[((b * 58 + hh) * 58 + ww) * 256 + ci] = 0;
}

// ------- kernel 3b: x NCHW fp32 -> padded NHWC bf16 (interior) -------
// grid (49 px-tiles, 4 ci-tiles, 32 b); 64px x 64ci tile via LDS transpose
__global__ __launch_bounds__(256)
void xcvt_kernel(const float* __restrict__ x, ushort_t* __restrict__ xp) {
    __shared__ float tile[64][65];
    const int px0 = blockIdx.x * 64;
    const int ci0 = blockIdx.y * 64;
    const int b   = blockIdx.z;
    const int row = threadIdx.x >> 6;    // 0..3
    const int lane = threadIdx.x & 63;
#pragma unroll
    for (int k = 0; k < 16; ++k) {
        int ci_l = row * 16 + k;
        tile[ci_l][lane] = x[(b * 256 + ci0 + ci_l) * 3136 + px0 + lane];
    }
    __syncthreads();
#pragma unroll
    for (int k = 0; k < 16; ++k) {
        int px_l = row * 16 + k;
        int px = px0 + px_l;
        int h = px / 56, w = px - h * 56;
        xp[((b * 58 + h + 1) * 58 + (w + 1)) * 256 + ci0 + lane] = f2bf(tile[lane][px_l]);
    }
}

// ------------- kernel 4: shift-conv as 9 GEMMs, bf16 MFMA, DMA-staged halo -------------
// grid: x = 28 (7 h-tiles x 4 w-tiles), y = 32 (batch), z = 2 (co block of 128)
// block: 256 threads = 4 waves; wave tile = 64 co x 64 px
__global__ __launch_bounds__(256, 3)
void conv_mfma2_kernel(const ushort_t* __restrict__ xp, const ushort_t* __restrict__ wt,
                       const float* __restrict__ alpha, const float* __restrict__ bias,
                       float* __restrict__ out) {
    // halo: [hr 0..9][hc 0..17][ci 0..31] bf16, unpadded (DMA lane-contiguous).
    // 720 real 16B slots + pad to 768 so clamped DMA lanes land in the pad.
    __shared__ __align__(16) ushort_t lds_x[768 * 8];

    const int tid  = threadIdx.x;
    const int b    = blockIdx.y;
    const int th   = blockIdx.x >> 2;
    const int tw   = blockIdx.x & 3;
    const int h0   = th * 8;
    const int w0   = tw * 16;
    const int co0  = blockIdx.z * 128;

    const int lane = tid & 63;
    const int wave = tid >> 6;
    const int l15  = lane & 15;
    const int quad = lane >> 4;
    const int wco  = (wave & 1) * 64;
    const int wrow = (wave >> 1) * 4;

    // ---- precompute 3 DMA slot descriptors per thread ----
    unsigned goff[3], loff[3];
#pragma unroll
    for (int t = 0; t < 3; ++t) {
        int s = tid + t * 256;
        int ss = (s < 720) ? s : 719;     // clamp: junk lands in LDS pad slots 720..767
        int hr = ss / 72;
        int rem = ss - hr * 72;
        int hc = rem >> 2, cig = rem & 3;
        int gh = h0 + hr;
        int gw = w0 + hc; if (gw > 57) gw = 57;   // clamp ragged right tile (unused cols)
        goff[t] = (unsigned)(((((b * 58 + gh) * 58 + gw) << 8) + (cig << 3)) * 2);
        loff[t] = (unsigned)((s & ~63) * 16);     // wave-uniform within the wave
    }
    const char* xpb = (const char*)xp;

    floatx4 acc[4][4];
#pragma unroll
    for (int i = 0; i < 4; ++i)
#pragma unroll
        for (int j = 0; j < 4; ++j)
            acc[i][j] = (floatx4){0.f, 0.f, 0.f, 0.f};

    // A fragment base offset (elements): wt[(r9*256 + co)*256 + cin + quad*8]
    const int aw = (co0 + wco + l15) * 256 + quad * 8;

    for (int cin0 = 0; cin0 < 256; cin0 += 32) {
        // ---- issue halo DMA: 12 wave-instructions total ----
#pragma unroll
        for (int t = 0; t < 3; ++t)
            g2l16(xpb + goff[t] + cin0 * 2, (char*)lds_x + loff[t]);

        // ---- prefetch A fragments for r9 = 0 (independent of LDS) ----
        short8 afc[4], afn[4];
#pragma unroll
        for (int i = 0; i < 4; ++i)
            afc[i] = *(const short8*)(wt + aw + i * 4096 + cin0);

        __syncthreads();   // drains DMA (vmcnt) + makes halo visible

        for (int r9 = 0; r9 < 9; ++r9) {
            if (r9 < 8) {
#pragma unroll
                for (int i = 0; i < 4; ++i)
                    afn[i] = *(const short8*)(wt + (r9 + 1) * 65536 + aw + i * 4096 + cin0);
            }
            const int kh = r9 / 3;
            const int kw = r9 - kh * 3;
            short8 bfv[4];
#pragma unroll
            for (int j = 0; j < 4; ++j)
                bfv[j] = *(const short8*)&lds_x[((wrow + j + kh) * 18 + (l15 + kw)) * 32 + quad * 8];
#pragma unroll
            for (int i = 0; i < 4; ++i)
#pragma unroll
                for (int j = 0; j < 4; ++j)
                    acc[i][j] = __builtin_amdgcn_mfma_f32_16x16x32_bf16(afc[i], bfv[j], acc[i][j], 0, 0, 0);
#pragma unroll
            for (int i = 0; i < 4; ++i) afc[i] = afn[i];
        }
        __syncthreads();   // protect lds_x before next cin-iter's DMA
    }

    // ---- epilogue: D row = quad*4+reg (co), col = l15 (w) ----
    const float a0 = alpha[0];
#pragma unroll
    for (int i = 0; i < 4; ++i) {
        int cob = co0 + wco + i * 16 + quad * 4;
#pragma unroll
        for (int j = 0; j < 4; ++j) {
            int hh = h0 + wrow + j;
            int ww = w0 + l15;
            if (ww < 56) {
#pragma unroll
                for (int r = 0; r < 4; ++r) {
                    int cog = cob + r;
                    out[((b * 256 + cog) * 56 + hh) * 56 + ww] = acc[i][j][r] * a0 + bias[cog];
                }
            }
        }
    }
}

// ------------- fallback conv (round-1, fp32-x staging) for small ws -------------
__global__ __launch_bounds__(256, 2)
void conv_mfma_fallback_kernel(const float* __restrict__ x, const ushort_t* __restrict__ wt,
                               const float* __restrict__ alpha, const float* __restrict__ bias,
                               float* __restrict__ out) {
    __shared__ __align__(16) ushort_t lds_x[10 * 18 * 40];
    __shared__ __align__(16) ushort_t lds_a[128 * 40];
    const int tid  = threadIdx.x;
    const int b    = blockIdx.y;
    const int th   = blockIdx.x >> 2;
    const int tw   = blockIdx.x & 3;
    const int h0   = th * 8;
    const int w0   = tw * 16;
    const int co0  = blockIdx.z * 128;
    const int lane = tid & 63;
    const int wave = tid >> 6;
    const int l15  = lane & 15;
    const int quad = lane >> 4;
    const int wco  = (wave & 1) * 64;
    const int wrow = (wave >> 1) * 4;
    floatx4 acc[4][4];
#pragma unroll
    for (int i = 0; i < 4; ++i)
#pragma unroll
        for (int j = 0; j < 4; ++j)
            acc[i][j] = (floatx4){0.f, 0.f, 0.f, 0.f};
    const int co_l = tid >> 1;
    const int half = tid & 1;
    for (int cin0 = 0; cin0 < 256; cin0 += 32) {
        for (int e = tid; e < 5760; e += 256) {
            int hc = e % 18;
            int t2 = e / 18;
            int hr = t2 % 10;
            int ci = t2 / 10;
            int hh = h0 - 1 + hr;
            int ww = w0 - 1 + hc;
            float v = 0.f;
            if (hh >= 0 && hh < 56 && ww >= 0 && ww < 56)
                v = x[((b * 256 + cin0 + ci) * 3136) + hh * 56 + ww];
            lds_x[(hr * 18 + hc) * 40 + ci] = f2bf(v);
        }
        for (int r9 = 0; r9 < 9; ++r9) {
            {
                const short8* src = (const short8*)(wt + (((r9 * 256) + co0 + co_l) * 256 + cin0 + half * 16));
                short8 v0 = src[0];
                short8 v1 = src[1];
                *(short8*)&lds_a[co_l * 40 + half * 16]     = v0;
                *(short8*)&lds_a[co_l * 40 + half * 16 + 8] = v1;
            }
            __syncthreads();
            const int kh = r9 / 3;
            const int kw = r9 % 3;
            short8 af[4], bf[4];
#pragma unroll
            for (int j = 0; j < 4; ++j)
                bf[j] = *(const short8*)&lds_x[((wrow + j + kh) * 18 + (l15 + kw)) * 40 + quad * 8];
#pragma unroll
            for (int i = 0; i < 4; ++i)
                af[i] = *(const short8*)&lds_a[(wco + i * 16 + l15) * 40 + quad * 8];
#pragma unroll
            for (int i = 0; i < 4; ++i)
#pragma unroll
                for (int j = 0; j < 4; ++j)
                    acc[i][j] = __builtin_amdgcn_mfma_f32_16x16x32_bf16(af[i], bf[j], acc[i][j], 0, 0, 0);
            __syncthreads();
        }
    }
    const float a0 = alpha[0];
#pragma unroll
    for (int i = 0; i < 4; ++i) {
        int cob = co0 + wco + i * 16 + quad * 4;
#pragma unroll
        for (int j = 0; j < 4; ++j) {
            int hh = h0 + wrow + j;
            int ww = w0 + l15;
            if (ww < 56) {
#pragma unroll
                for (int r = 0; r < 4; ++r) {
                    int cog = cob + r;
                    out[((b * 256 + cog) * 56 + hh) * 56 + ww] = acc[i][j][r] * a0 + bias[cog];
                }
            }
        }
    }
}

extern "C" void kernel_launch(void* const* d_in, const int* in_sizes, int n_in,
                              void* d_out, int out_size, void* d_ws, size_t ws_size,
                              hipStream_t stream) {
    const float* x      = (const float*)d_in[0];
    const float* weight = (const float*)d_in[1];
    const float* alpha  = (const float*)d_in[2];
    const float* bias   = (const float*)d_in[3];
    float* out = (float*)d_out;

    double*   dsum = (double*)d_ws;
    ushort_t* wt   = (ushort_t*)((char*)d_ws + 256);               // 1179648 B
    ushort_t* xp   = (ushort_t*)((char*)d_ws + 256 + 1179648);     // 55115776 B
    const size_t NEED = 256 + 1179648 + 55115776;

    hipMemsetAsync(d_ws, 0, 16, stream);
    absmean_kernel<<<256, 256, 0, stream>>>(weight, dsum);
    ternarize_kernel<<<N_W / 256, 256, 0, stream>>>(weight, dsum, wt);

    dim3 grid(28, 32, 2);
    if (ws_size >= NEED) {
        border_zero_kernel<<<7296, 256, 0, stream>>>(xp);
        dim3 cgrid(49, 4, 32);
        xcvt_kernel<<<cgrid, 256, 0, stream>>>(x, xp);
        conv_mfma2_kernel<<<grid, 256, 0, stream>>>(xp, wt, alpha, bias, out);
    } else {
        conv_mfma_fallback_kernel<<<grid, 256, 0, stream>>>(x, wt, alpha, bias, out);
    }
}

// Round 3
// 362.789 us; speedup vs baseline: 1.3460x; 1.3285x over previous
//
#include <hip/hip_runtime.h>

typedef unsigned short ushort_t;
typedef short short8 __attribute__((ext_vector_type(8)));
typedef unsigned short ushort8 __attribute__((ext_vector_type(8)));
typedef float floatx4 __attribute__((ext_vector_type(4)));

#define N_W 589824   // 256*256*3*3

static __device__ __forceinline__ unsigned short f2bf(float f) {
    unsigned int u = __float_as_uint(f);
    u = (u + 0x7FFFu + ((u >> 16) & 1u)) >> 16;   // round-to-nearest-even
    return (unsigned short)u;
}

// async 16B global -> LDS DMA; data lands at lds_base + lane*16 (wave-uniform base)
static __device__ __forceinline__ void g2l16(const void* g, void* lds_base_uniform) {
    __builtin_amdgcn_global_load_lds(
        (__attribute__((address_space(1))) void*)g,
        (__attribute__((address_space(3))) void*)lds_base_uniform,
        16, 0, 0);
}

// ---------------- kernel 1: sum(|w|) -> double in ws[0] ----------------
__global__ void absmean_kernel(const float* __restrict__ w, double* __restrict__ dsum) {
    int tid = blockIdx.x * blockDim.x + threadIdx.x;
    int stride = gridDim.x * blockDim.x;
    float local = 0.f;
    for (int i = tid; i < N_W; i += stride) local += fabsf(w[i]);
    for (int off = 32; off > 0; off >>= 1)
        local += __shfl_down(local, off, 64);
    __shared__ float part[4];
    int lane = threadIdx.x & 63, wv = threadIdx.x >> 6;
    if (lane == 0) part[wv] = local;
    __syncthreads();
    if (threadIdx.x == 0) {
        float s = part[0] + part[1] + part[2] + part[3];
        atomicAdd(dsum, (double)s);  // double: delta bit-stable vs np ref
    }
}

// -------- kernel 2: ternarize -> MFMA-fragment-ordered layout --------
// wtf index: [cin_blk 8][r9 9][g(co64) 4][i 4][q 4][l 16][e 8]
__global__ void ternarize_frag_kernel(const float* __restrict__ w, const double* __restrict__ dsum,
                                      ushort_t* __restrict__ wtf) {
    int o = blockIdx.x * 256 + threadIdx.x;
    float delta = 0.7f * (float)(*dsum / (double)N_W);
    int e   = o & 7;
    int l   = (o >> 3) & 15;
    int q   = (o >> 7) & 3;
    int i   = (o >> 9) & 3;
    int g   = (o >> 11) & 3;
    int t13 = o >> 13;               // 0..71
    int r9  = t13 % 9;
    int cb  = t13 / 9;
    int co  = g * 64 + i * 16 + l;
    int cin = cb * 32 + q * 8 + e;
    float v = w[(co * 256 + cin) * 9 + r9];
    float t = (v > delta) ? 1.f : ((v < -delta) ? -1.f : 0.f);
    wtf[o] = f2bf(t);
}

// -------- kernel 2b (fallback path): old [r][co][cin] layout --------
__global__ void ternarize_kernel(const float* __restrict__ w, const double* __restrict__ dsum,
                                 ushort_t* __restrict__ wt) {
    int o = blockIdx.x * 256 + threadIdx.x;
    float delta = 0.7f * (float)(*dsum / (double)N_W);
    int cin = o & 255;
    int co  = (o >> 8) & 255;
    int r   = o >> 16;
    float v = w[(co * 256 + cin) * 9 + r];
    float t = (v > delta) ? 1.f : ((v < -delta) ? -1.f : 0.f);
    wt[o] = f2bf(t);
}

// ------- kernel 3a: zero the 1px border of padded NHWC bf16 x (ushort8 stores) -------
__global__ void border_zero_kernel(ushort_t* __restrict__ xp) {
    int e = blockIdx.x * 256 + threadIdx.x;          // 32*228*32 = 233472 chunks
    int cg   = e & 31;                               // ci chunk of 8
    int rest = e >> 5;
    int pid  = rest % 228;
    int b    = rest / 228;
    int hh, ww;
    if (pid < 58)       { hh = 0;  ww = pid; }
    else if (pid < 116) { hh = 57; ww = pid - 58; }
    else {
        int p = pid - 116;
        hh = 1 + (p >> 1);
        ww = (p & 1) ? 57 : 0;
    }
    ushort8 z = (ushort8){0,0,0,0,0,0,0,0};
    *(ushort8*)&xp[(((b * 58 + hh) * 58 + ww) << 8) + cg * 8] = z;
}

// ------- kernel 3b: x NCHW fp32 -> padded NHWC bf16 interior, 16B stores -------
__global__ __launch_bounds__(256)
void xcvt_kernel(const float* __restrict__ x, ushort_t* __restrict__ xp) {
    __shared__ float tile[64][65];
    const int px0 = blockIdx.x * 64;
    const int ci0 = blockIdx.y * 64;
    const int b   = blockIdx.z;
    const int row  = threadIdx.x >> 6;
    const int lane = threadIdx.x & 63;
#pragma unroll
    for (int k = 0; k < 16; ++k) {
        int ci_l = row * 16 + k;
        tile[ci_l][lane] = x[(b * 256 + ci0 + ci_l) * 3136 + px0 + lane];
    }
    __syncthreads();
#pragma unroll
    for (int p = 0; p < 2; ++p) {
        int c    = threadIdx.x + p * 256;   // 0..511
        int px_l = c >> 3;
        int cg   = c & 7;
        int px = px0 + px_l;
        int h = px / 56, w = px - h * 56;
        ushort8 v;
#pragma unroll
        for (int j = 0; j < 8; ++j) v[j] = f2bf(tile[cg * 8 + j][px_l]);
        *(ushort8*)&xp[(((b * 58 + h + 1) * 58 + (w + 1)) << 8) + ci0 + cg * 8] = v;
    }
}

// ------------- kernel 4: shift-conv, bf16 MFMA, dbuf DMA halo + pipelined A -------------
// grid: x = 28 (7 h x 4 w tiles), y = 32 (b), z = 2 (co128); block 256 = 4 waves
__global__ __launch_bounds__(256, 3)
void conv_mfma3_kernel(const ushort_t* __restrict__ xp, const ushort_t* __restrict__ wtf,
                       const float* __restrict__ alpha, const float* __restrict__ bias,
                       float* __restrict__ out) {
    // two halo buffers: [hr 10][hc 18][ci 32] bf16 = 720 slots of 16B, padded to 768
    __shared__ __align__(16) ushort_t lds_x[2 * 768 * 8];

    const int tid  = threadIdx.x;
    const int b    = blockIdx.y;
    const int th   = blockIdx.x >> 2;
    const int tw   = blockIdx.x & 3;
    const int h0   = th * 8;
    const int w0   = tw * 16;
    const int co0  = blockIdx.z * 128;

    const int lane = tid & 63;
    const int wave = tid >> 6;
    const int l15  = lane & 15;
    const int quad = lane >> 4;
    const int wco  = (wave & 1) * 64;
    const int wrow = (wave >> 1) * 4;

    // ---- DMA slot descriptors (3 per thread) ----
    unsigned goff[3], loff[3];
#pragma unroll
    for (int t = 0; t < 3; ++t) {
        int s = tid + t * 256;
        int ss = (s < 720) ? s : 719;                 // clamp into LDS pad slots
        int hr = ss / 72;
        int rem = ss - hr * 72;
        int hc = rem >> 2, cig = rem & 3;
        int gh = h0 + hr;
        int gw = w0 + hc; if (gw > 57) gw = 57;       // ragged right tile clamp
        goff[t] = (unsigned)(((((b * 58 + gh) * 58 + gw) << 8) + (cig << 3)) * 2);
        loff[t] = (unsigned)((s & ~63) * 16);         // wave-uniform base
    }
    const char* xpb = (const char*)xp;

    floatx4 acc[4][4];
#pragma unroll
    for (int i = 0; i < 4; ++i)
#pragma unroll
        for (int j = 0; j < 4; ++j)
            acc[i][j] = (floatx4){0.f, 0.f, 0.f, 0.f};

    // A-fragment base: wtf[((cb*9 + r9)*4 + gsel)*2048 + i*512 + lane*8]
    const int gsel = blockIdx.z * 2 + (wave & 1);
    const ushort_t* wbase = wtf + gsel * 2048 + lane * 8;

    // prologue: halo DMA for cin_blk 0 into buf 0
#pragma unroll
    for (int t = 0; t < 3; ++t)
        g2l16(xpb + goff[t], (char*)lds_x + loff[t]);

    int cur = 0;
    for (int cb = 0; cb < 8; ++cb) {
        const ushort_t* wcb = wbase + cb * (9 * 4 * 2048);
        // A pipeline prologue: r9 = 0,1,2 (global, no LDS dep)
        short8 af[3][4];
#pragma unroll
        for (int r = 0; r < 3; ++r)
#pragma unroll
            for (int i = 0; i < 4; ++i)
                af[r][i] = *(const short8*)(wcb + r * 8192 + i * 512);

        __syncthreads();   // drains DMA for buf[cur]

        // issue next halo DMA into the other buffer (hidden behind compute)
        if (cb < 7) {
#pragma unroll
            for (int t = 0; t < 3; ++t)
                g2l16(xpb + goff[t] + (cb + 1) * 64, (char*)lds_x + loff[t] + (cur ^ 1) * 12288);
        }

        const ushort_t* xb = lds_x + cur * 6144;
#pragma unroll
        for (int r9 = 0; r9 < 9; ++r9) {
            const int kh = r9 / 3;
            const int kw = r9 - kh * 3;
            short8 bfv[4];
#pragma unroll
            for (int j = 0; j < 4; ++j)
                bfv[j] = *(const short8*)&xb[((wrow + j + kh) * 18 + (l15 + kw)) * 32 + quad * 8];
#pragma unroll
            for (int i = 0; i < 4; ++i)
#pragma unroll
                for (int j = 0; j < 4; ++j)
                    acc[i][j] = __builtin_amdgcn_mfma_f32_16x16x32_bf16(af[r9 % 3][i], bfv[j], acc[i][j], 0, 0, 0);
            if (r9 < 6) {
#pragma unroll
                for (int i = 0; i < 4; ++i)
                    af[r9 % 3][i] = *(const short8*)(wcb + (r9 + 3) * 8192 + i * 512);
            }
        }
        cur ^= 1;
    }

    // ---- epilogue: D row = quad*4+reg (co), col = l15 (w) ----
    const float a0 = alpha[0];
#pragma unroll
    for (int i = 0; i < 4; ++i) {
        int cob = co0 + wco + i * 16 + quad * 4;
#pragma unroll
        for (int j = 0; j < 4; ++j) {
            int hh = h0 + wrow + j;
            int ww = w0 + l15;
            if (ww < 56) {
#pragma unroll
                for (int r = 0; r < 4; ++r) {
                    int cog = cob + r;
                    out[((b * 256 + cog) * 56 + hh) * 56 + ww] = acc[i][j][r] * a0 + bias[cog];
                }
            }
        }
    }
}

// ------------- fallback conv (fp32-x staging, old wt layout) -------------
__global__ __launch_bounds__(256, 2)
void conv_mfma_fallback_kernel(const float* __restrict__ x, const ushort_t* __restrict__ wt,
                               const float* __restrict__ alpha, const float* __restrict__ bias,
                               float* __restrict__ out) {
    __shared__ __align__(16) ushort_t lds_x[10 * 18 * 40];
    __shared__ __align__(16) ushort_t lds_a[128 * 40];
    const int tid  = threadIdx.x;
    const int b    = blockIdx.y;
    const int th   = blockIdx.x >> 2;
    const int tw   = blockIdx.x & 3;
    const int h0   = th * 8;
    const int w0   = tw * 16;
    const int co0  = blockIdx.z * 128;
    const int lane = tid & 63;
    const int wave = tid >> 6;
    const int l15  = lane & 15;
    const int quad = lane >> 4;
    const int wco  = (wave & 1) * 64;
    const int wrow = (wave >> 1) * 4;
    floatx4 acc[4][4];
#pragma unroll
    for (int i = 0; i < 4; ++i)
#pragma unroll
        for (int j = 0; j < 4; ++j)
            acc[i][j] = (floatx4){0.f, 0.f, 0.f, 0.f};
    const int co_l = tid >> 1;
    const int half = tid & 1;
    for (int cin0 = 0; cin0 < 256; cin0 += 32) {
        for (int e = tid; e < 5760; e += 256) {
            int hc = e % 18;
            int t2 = e / 18;
            int hr = t2 % 10;
            int ci = t2 / 10;
            int hh = h0 - 1 + hr;
            int ww = w0 - 1 + hc;
            float v = 0.f;
            if (hh >= 0 && hh < 56 && ww >= 0 && ww < 56)
                v = x[((b * 256 + cin0 + ci) * 3136) + hh * 56 + ww];
            lds_x[(hr * 18 + hc) * 40 + ci] = f2bf(v);
        }
        for (int r9 = 0; r9 < 9; ++r9) {
            {
                const short8* src = (const short8*)(wt + (((r9 * 256) + co0 + co_l) * 256 + cin0 + half * 16));
                short8 v0 = src[0];
                short8 v1 = src[1];
                *(short8*)&lds_a[co_l * 40 + half * 16]     = v0;
                *(short8*)&lds_a[co_l * 40 + half * 16 + 8] = v1;
            }
            __syncthreads();
            const int kh = r9 / 3;
            const int kw = r9 % 3;
            short8 af[4], bf[4];
#pragma unroll
            for (int j = 0; j < 4; ++j)
                bf[j] = *(const short8*)&lds_x[((wrow + j + kh) * 18 + (l15 + kw)) * 40 + quad * 8];
#pragma unroll
            for (int i = 0; i < 4; ++i)
                af[i] = *(const short8*)&lds_a[(wco + i * 16 + l15) * 40 + quad * 8];
#pragma unroll
            for (int i = 0; i < 4; ++i)
#pragma unroll
                for (int j = 0; j < 4; ++j)
                    acc[i][j] = __builtin_amdgcn_mfma_f32_16x16x32_bf16(af[i], bf[j], acc[i][j], 0, 0, 0);
            __syncthreads();
        }
    }
    const float a0 = alpha[0];
#pragma unroll
    for (int i = 0; i < 4; ++i) {
        int cob = co0 + wco + i * 16 + quad * 4;
#pragma unroll
        for (int j = 0; j < 4; ++j) {
            int hh = h0 + wrow + j;
            int ww = w0 + l15;
            if (ww < 56) {
#pragma unroll
                for (int r = 0; r < 4; ++r) {
                    int cog = cob + r;
                    out[((b * 256 + cog) * 56 + hh) * 56 + ww] = acc[i][j][r] * a0 + bias[cog];
                }
            }
        }
    }
}

extern "C" void kernel_launch(void* const* d_in, const int* in_sizes, int n_in,
                              void* d_out, int out_size, void* d_ws, size_t ws_size,
                              hipStream_t stream) {
    const float* x      = (const float*)d_in[0];
    const float* weight = (const float*)d_in[1];
    const float* alpha  = (const float*)d_in[2];
    const float* bias   = (const float*)d_in[3];
    float* out = (float*)d_out;

    double*   dsum = (double*)d_ws;
    ushort_t* wtf  = (ushort_t*)((char*)d_ws + 256);               // 1179648 B
    ushort_t* xp   = (ushort_t*)((char*)d_ws + 256 + 1179648);     // 55115776 B
    const size_t NEED = 256 + 1179648 + 55115776;

    hipMemsetAsync(d_ws, 0, 16, stream);
    absmean_kernel<<<256, 256, 0, stream>>>(weight, dsum);

    dim3 grid(28, 32, 2);
    if (ws_size >= NEED) {
        ternarize_frag_kernel<<<N_W / 256, 256, 0, stream>>>(weight, dsum, wtf);
        border_zero_kernel<<<912, 256, 0, stream>>>(xp);
        dim3 cgrid(49, 4, 32);
        xcvt_kernel<<<cgrid, 256, 0, stream>>>(x, xp);
        conv_mfma3_kernel<<<grid, 256, 0, stream>>>(xp, wtf, alpha, bias, out);
    } else {
        ternarize_kernel<<<N_W / 256, 256, 0, stream>>>(weight, dsum, wtf);
        conv_mfma_fallback_kernel<<<grid, 256, 0, stream>>>(x, wtf, alpha, bias, out);
    }
}